// Round 4
// baseline (242.823 us; speedup 1.0000x reference)
//
#include <hip/hip_runtime.h>
#include <hip/hip_cooperative_groups.h>

namespace cg = cooperative_groups;

#define MH 28
#define MW 28
#define CC 64
#define GG 4
#define NB 32

// ws layout (coop path):
//   [0, 7168)        : uint2 slots[896]  (overwritten each call)
//   [8192, +25088)   : any-of-g map, uchar (B,28,28)
// fallback path additionally:
//   [65536, +100352) : coarse mask, uchar (B,G,28,28)

// ================= cooperative fused kernel =================
__global__ __launch_bounds__(256, 4) void masker_coop(
    const float* __restrict__ x, const float* __restrict__ w,
    const float* __restrict__ bias, const float* __restrict__ gum,
    float* __restrict__ out_mask, float* __restrict__ out_dil,
    float* __restrict__ out_scalars,
    uint2* __restrict__ slots, unsigned char* __restrict__ anyb)
{
    cg::grid_group grid = cg::this_grid();
    const int blk = blockIdx.x;
    const int b   = blk / MH;
    const int ch  = blk - b * MH;
    const int t   = threadIdx.x;

    __shared__ float pooled[CC][MW];
    __shared__ float wlds[8 * CC];
    __shared__ float logits[8][MW];
    __shared__ float dec[GG][MW];
    __shared__ float R[3][MW + 2];
    __shared__ unsigned int sm[4], sd[4];

    // ---- prefetch small operands into registers before the big load phase ----
    float g0 = 0.f, g1 = 0.f, bo = 0.f;
    if (t < GG * MW) {
        int g = t / MW, cw = t - g * MW;
        g0 = gum[((((size_t)b * 2 + 0) * GG + g) * MH + ch) * MW + cw];
        g1 = gum[((((size_t)b * 2 + 1) * GG + g) * MH + ch) * MW + cw];
    }
    if (t < 8 * MW) bo = bias[t / MW];
    if (t < 128) ((float4*)wlds)[t] = ((const float4*)w)[t];

    // ---- phase 1: 4x4 average pool, 1792 cells, 7/thread, float4 loads ----
    const float* xb = x + (size_t)b * CC * 112 * 112 + (size_t)(4 * ch) * 112;
    #pragma unroll
    for (int k = 0; k < 7; ++k) {
        int p  = t + 256 * k;              // 0..1791
        int c  = p / MW;
        int cw = p - c * MW;
        const float* base = xb + (size_t)c * (112 * 112) + 4 * cw;
        float s = 0.f;
        #pragma unroll
        for (int hh = 0; hh < 4; ++hh) {
            float4 v = *(const float4*)(base + hh * 112);
            s += v.x + v.y + v.z + v.w;
        }
        pooled[c][cw] = s * 0.0625f;
    }
    __syncthreads();

    // ---- projection: 8 outputs x 28 cols ----
    if (t < 8 * MW) {
        int o = t / MW, cw = t - o * MW;
        float acc = bo;
        #pragma unroll
        for (int c = 0; c < CC; ++c)
            acc += pooled[c][cw] * wlds[o * CC + c];
        logits[o][cw] = acc;
    }
    __syncthreads();

    // ---- gumbel decision (T>0 scaling is argmax-invariant; ties -> idx 0) ----
    unsigned int local_m = 0;
    if (t < GG * MW) {
        int g = t / MW, cw = t - g * MW;
        float mv = (logits[g][cw] + g0 >= logits[g + 4][cw] + g1) ? 1.f : 0.f;
        dec[g][cw] = mv;
        local_m = (unsigned int)mv;
    }
    __syncthreads();
    if (t < MW) {
        float a = fmaxf(fmaxf(dec[0][t], dec[1][t]), fmaxf(dec[2][t], dec[3][t]));
        R[1][t + 1] = a;
        anyb[((size_t)b * MH + ch) * MW + t] = (unsigned char)a;
    }

    grid.sync();   // any-map globally visible; dec/R stay live in LDS

    // ---- phase 2: neighbor rows, dilate, outputs, counts ----
    if (t < MW) {
        float a  = R[1][t + 1];
        float am = (ch > 0)      ? (float)anyb[((size_t)b * MH + ch - 1) * MW + t] : 0.f;
        float ap = (ch < MH - 1) ? (float)anyb[((size_t)b * MH + ch + 1) * MW + t] : 0.f;
        R[0][t + 1] = fmaxf(a, am);
        R[2][t + 1] = fmaxf(a, ap);
    }
    if (t < 3) { R[t][0] = 0.f; R[t][MW + 1] = 0.f; }
    __syncthreads();

    unsigned int local_d = 0;
    #pragma unroll
    for (int k = 0; k < 7; ++k) {
        int idx = t + 256 * k;             // g(4) x hh(4) x w(112)
        int g   = idx / 448;
        int rem = idx - g * 448;
        int hh  = rem / 112;
        int wfi = rem - hh * 112;
        int cw  = wfi >> 2;
        int wm  = wfi & 3;
        int rv  = (hh == 0) ? 0 : (hh == 3 ? 2 : 1);
        float d;
        if (wm == 0)      d = fmaxf(R[rv][cw],     R[rv][cw + 1]);
        else if (wm == 3) d = fmaxf(R[rv][cw + 1], R[rv][cw + 2]);
        else              d = R[rv][cw + 1];
        float mv = dec[g][cw];
        size_t o = (((size_t)b * GG + g) * 112 + (4 * ch + hh)) * 112 + wfi;
        out_mask[o] = mv;
        out_dil[o]  = d;
        local_d += (d > 0.5f) ? 1u : 0u;
    }

    #pragma unroll
    for (int off = 32; off; off >>= 1) {
        local_m += __shfl_down(local_m, off);
        local_d += __shfl_down(local_d, off);
    }
    if ((t & 63) == 0) { sm[t >> 6] = local_m; sd[t >> 6] = local_d; }
    __syncthreads();
    if (t == 0) {
        uint2 v;
        v.x = sm[0] + sm[1] + sm[2] + sm[3];
        v.y = sd[0] + sd[1] + sd[2] + sd[3];
        slots[blk] = v;                    // overwrite, no atomics
    }

    grid.sync();   // all slots visible

    if (blk == 0) {
        unsigned int m = 0, d = 0;
        for (int i = t; i < NB * MH; i += 256) {
            uint2 v = slots[i]; m += v.x; d += v.y;
        }
        #pragma unroll
        for (int off = 32; off; off >>= 1) {
            m += __shfl_down(m, off);
            d += __shfl_down(d, off);
        }
        if ((t & 63) == 0) { sm[t >> 6] = m; sd[t >> 6] = d; }
        __syncthreads();
        if (t == 0) {
            out_scalars[0] = (float)(sm[0] + sm[1] + sm[2] + sm[3]) / 100352.0f;
            out_scalars[1] = (float)(sd[0] + sd[1] + sd[2] + sd[3]) / 1605632.0f;
            out_scalars[2] = 501760.0f;
        }
    }
}

// ================= fallback: round-2 3-kernel path =================
__global__ __launch_bounds__(256) void masker_stage1(
    const float* __restrict__ x, const float* __restrict__ w,
    const float* __restrict__ bias, const float* __restrict__ gum,
    unsigned char* __restrict__ coarse, unsigned char* __restrict__ anyb)
{
    int b = blockIdx.x / MH, ch = blockIdx.x % MH, t = threadIdx.x;
    __shared__ float pooled[CC][MW];
    __shared__ float wlds[8 * CC];
    __shared__ float logits[8][MW];
    __shared__ unsigned char mlds[GG][MW];

    float g0 = 0.f, g1 = 0.f, bo = 0.f;
    if (t < GG * MW) {
        int g = t / MW, cw = t - g * MW;
        g0 = gum[((((size_t)b * 2 + 0) * GG + g) * MH + ch) * MW + cw];
        g1 = gum[((((size_t)b * 2 + 1) * GG + g) * MH + ch) * MW + cw];
    }
    if (t < 8 * MW) bo = bias[t / MW];
    if (t < 128) ((float4*)wlds)[t] = ((const float4*)w)[t];

    const float* xb = x + (size_t)b * CC * 112 * 112 + (size_t)(4 * ch) * 112;
    #pragma unroll
    for (int k = 0; k < 7; ++k) {
        int p = t + 256 * k, c = p / MW, cw = p - c * MW;
        const float* base = xb + (size_t)c * (112 * 112) + 4 * cw;
        float s = 0.f;
        #pragma unroll
        for (int hh = 0; hh < 4; ++hh) {
            float4 v = *(const float4*)(base + hh * 112);
            s += v.x + v.y + v.z + v.w;
        }
        pooled[c][cw] = s * 0.0625f;
    }
    __syncthreads();
    if (t < 8 * MW) {
        int o = t / MW, cw = t - o * MW;
        float acc = bo;
        #pragma unroll
        for (int c = 0; c < CC; ++c) acc += pooled[c][cw] * wlds[o * CC + c];
        logits[o][cw] = acc;
    }
    __syncthreads();
    if (t < GG * MW) {
        int g = t / MW, cw = t - g * MW;
        unsigned char mv = (logits[g][cw] + g0 >= logits[g + 4][cw] + g1) ? 1u : 0u;
        mlds[g][cw] = mv;
        coarse[(((size_t)b * GG + g) * MH + ch) * MW + cw] = mv;
    }
    __syncthreads();
    if (t < MW)
        anyb[((size_t)b * MH + ch) * MW + t] =
            mlds[0][t] | mlds[1][t] | mlds[2][t] | mlds[3][t];
}

__global__ __launch_bounds__(256) void masker_stage2(
    const unsigned char* __restrict__ coarse,
    const unsigned char* __restrict__ anyb,
    float* __restrict__ out_mask, float* __restrict__ out_dil,
    uint2* __restrict__ slots)
{
    int b = blockIdx.x / MH, ch = blockIdx.x % MH, t = threadIdx.x;
    __shared__ float carr[GG][MW];
    __shared__ float R[3][MW + 2];
    __shared__ unsigned int sm[4], sd[4];

    unsigned int local_m = 0;
    if (t < GG * MW) {
        int g = t / MW, cw = t - g * MW;
        unsigned char mv = coarse[(((size_t)b * GG + g) * MH + ch) * MW + cw];
        carr[g][cw] = (float)mv;
        local_m = mv;
    }
    if (t < MW) {
        float a  = (float)anyb[((size_t)b * MH + ch) * MW + t];
        float am = (ch > 0)      ? (float)anyb[((size_t)b * MH + ch - 1) * MW + t] : 0.f;
        float ap = (ch < MH - 1) ? (float)anyb[((size_t)b * MH + ch + 1) * MW + t] : 0.f;
        R[0][t + 1] = fmaxf(a, am);
        R[1][t + 1] = a;
        R[2][t + 1] = fmaxf(a, ap);
    }
    if (t < 3) { R[t][0] = 0.f; R[t][MW + 1] = 0.f; }
    __syncthreads();

    unsigned int local_d = 0;
    #pragma unroll
    for (int k = 0; k < 7; ++k) {
        int idx = t + 256 * k;
        int g = idx / 448, rem = idx - g * 448;
        int hh = rem / 112, wfi = rem - hh * 112;
        int cw = wfi >> 2, wm = wfi & 3;
        int rv = (hh == 0) ? 0 : (hh == 3 ? 2 : 1);
        float d;
        if (wm == 0)      d = fmaxf(R[rv][cw],     R[rv][cw + 1]);
        else if (wm == 3) d = fmaxf(R[rv][cw + 1], R[rv][cw + 2]);
        else              d = R[rv][cw + 1];
        float mv = carr[g][cw];
        size_t o = (((size_t)b * GG + g) * 112 + (4 * ch + hh)) * 112 + wfi;
        out_mask[o] = mv;
        out_dil[o]  = d;
        local_d += (d > 0.5f) ? 1u : 0u;
    }
    #pragma unroll
    for (int off = 32; off; off >>= 1) {
        local_m += __shfl_down(local_m, off);
        local_d += __shfl_down(local_d, off);
    }
    if ((t & 63) == 0) { sm[t >> 6] = local_m; sd[t >> 6] = local_d; }
    __syncthreads();
    if (t == 0) {
        uint2 v;
        v.x = sm[0] + sm[1] + sm[2] + sm[3];
        v.y = sd[0] + sd[1] + sd[2] + sd[3];
        slots[blockIdx.x] = v;
    }
}

__global__ __launch_bounds__(256) void masker_stage3(
    const uint2* __restrict__ slots, float* __restrict__ out_scalars)
{
    int t = threadIdx.x;
    unsigned int m = 0, d = 0;
    for (int i = t; i < NB * MH; i += 256) { uint2 v = slots[i]; m += v.x; d += v.y; }
    #pragma unroll
    for (int off = 32; off; off >>= 1) { m += __shfl_down(m, off); d += __shfl_down(d, off); }
    __shared__ unsigned int sm[4], sd[4];
    if ((t & 63) == 0) { sm[t >> 6] = m; sd[t >> 6] = d; }
    __syncthreads();
    if (t == 0) {
        out_scalars[0] = (float)(sm[0] + sm[1] + sm[2] + sm[3]) / 100352.0f;
        out_scalars[1] = (float)(sd[0] + sd[1] + sd[2] + sd[3]) / 1605632.0f;
        out_scalars[2] = 501760.0f;
    }
}

extern "C" void kernel_launch(void* const* d_in, const int* in_sizes, int n_in,
                              void* d_out, int out_size, void* d_ws, size_t ws_size,
                              hipStream_t stream) {
    const float* x    = (const float*)d_in[0];
    const float* w    = (const float*)d_in[1];
    const float* bias = (const float*)d_in[2];
    const float* gum  = (const float*)d_in[3];

    float* out = (float*)d_out;
    const size_t n_mask = (size_t)NB * GG * 112 * 112;   // 1,605,632
    float* out_mask = out;
    float* out_dil  = out + n_mask;
    float* out_scal = out + 2 * n_mask;

    uint2*         slots  = (uint2*)d_ws;
    unsigned char* anyb   = (unsigned char*)d_ws + 8192;
    unsigned char* coarse = (unsigned char*)d_ws + 65536;   // fallback only

    void* args[] = { (void*)&x, (void*)&w, (void*)&bias, (void*)&gum,
                     (void*)&out_mask, (void*)&out_dil, (void*)&out_scal,
                     (void*)&slots, (void*)&anyb };

    hipError_t err = hipLaunchCooperativeKernel(
        reinterpret_cast<void*>(&masker_coop),
        dim3(NB * MH), dim3(256), args, 0, stream);

    if (err != hipSuccess) {
        // fallback: proven round-2 path
        dim3 grid(NB * MH);
        masker_stage1<<<grid, 256, 0, stream>>>(x, w, bias, gum, coarse, anyb);
        masker_stage2<<<grid, 256, 0, stream>>>(coarse, anyb, out_mask, out_dil, slots);
        masker_stage3<<<1, 256, 0, stream>>>(slots, out_scal);
    }
}

// Round 5
// 36.835 us; speedup vs baseline: 6.5922x; 6.5922x over previous
//
#include <hip/hip_runtime.h>

#define MH 28
#define MW 28
#define CC 64
#define GG 4
#define NB 32
#define HW14 14   // half coarse row

// ws layout:
//   [0, 14336)          : uint2 slots[1792] (overwritten, no init)
//   [16384, +100352)    : coarse mask, uchar (B,G,28,28)
//   [116736, +25088)    : any-of-g map, uchar (B,28,28)

// ---------- K1: pool + project + decide, one (b, coarse-row, col-half) per block ----------
// grid: B*MH*2 = 1792 blocks (exactly 7 per CU), 256 threads
__global__ __launch_bounds__(256) void masker_k1(
    const float* __restrict__ x, const float* __restrict__ w,
    const float* __restrict__ bias, const float* __restrict__ gum,
    unsigned char* __restrict__ coarse, unsigned char* __restrict__ anyb)
{
    const int blk = blockIdx.x;
    const int hc  = blk & 1;          // column half: cols [hc*14, hc*14+14)
    const int bc  = blk >> 1;         // b*28 + ch
    const int b   = bc / MH;
    const int ch  = bc - b * MH;
    const int t   = threadIdx.x;

    __shared__ float pooled[CC][HW14];     // 64 x 14
    __shared__ float wlds[8 * CC];         // full 8x64 weight
    __shared__ float logits[8][HW14];
    __shared__ unsigned char mlds[GG][HW14];

    // ---- prefetch small operands into registers ----
    float g0 = 0.f, g1 = 0.f, bo = 0.f;
    if (t < GG * HW14) {
        int g = t / HW14, cw = hc * HW14 + (t - (t / HW14) * HW14);
        g0 = gum[((((size_t)b * 2 + 0) * GG + g) * MH + ch) * MW + cw];
        g1 = gum[((((size_t)b * 2 + 1) * GG + g) * MH + ch) * MW + cw];
    }
    if (t < 8 * HW14) bo = bias[t / HW14];
    if (t < 128) ((float4*)wlds)[t] = ((const float4*)w)[t];

    // ---- 4x4 average pool: 896 cells = c(64) x cwl(14), 3.5/thread ----
    const float* xb = x + (size_t)b * CC * 112 * 112
                        + (size_t)(4 * ch) * 112 + 4 * (hc * HW14);
    #pragma unroll
    for (int k = 0; k < 4; ++k) {
        int p = t + 256 * k;
        if (p < CC * HW14) {
            int c   = p / HW14;
            int cwl = p - c * HW14;
            const float* base = xb + (size_t)c * (112 * 112) + 4 * cwl;
            float s = 0.f;
            #pragma unroll
            for (int hh = 0; hh < 4; ++hh) {
                float4 v = *(const float4*)(base + hh * 112);
                s += v.x + v.y + v.z + v.w;
            }
            pooled[c][cwl] = s * 0.0625f;
        }
    }
    __syncthreads();

    // ---- projection: 8 outputs x 14 cols, full 64-channel dot ----
    if (t < 8 * HW14) {
        int o = t / HW14, cwl = t - o * HW14;
        float acc = bo;
        #pragma unroll
        for (int c = 0; c < CC; ++c)
            acc += pooled[c][cwl] * wlds[o * CC + c];
        logits[o][cwl] = acc;
    }
    __syncthreads();

    // ---- gumbel decision (T>0 scale is argmax-invariant; ties -> idx 0) ----
    if (t < GG * HW14) {
        int g = t / HW14, cwl = t - g * HW14;
        unsigned char mv = (logits[g][cwl] + g0 >= logits[g + 4][cwl] + g1) ? 1u : 0u;
        mlds[g][cwl] = mv;
        coarse[(((size_t)b * GG + g) * MH + ch) * MW + hc * HW14 + cwl] = mv;
    }
    __syncthreads();
    if (t < HW14) {
        unsigned char a = mlds[0][t] | mlds[1][t] | mlds[2][t] | mlds[3][t];
        anyb[((size_t)b * MH + ch) * MW + hc * HW14 + t] = a;
    }
}

// ---------- K2: upsample + dilate + outputs + per-block counts ----------
// grid: B*MH*2 = 1792 blocks (hv = which hh-pair), 256 threads
__global__ __launch_bounds__(256) void masker_k2(
    const unsigned char* __restrict__ coarse,
    const unsigned char* __restrict__ anyb,
    float* __restrict__ out_mask, float* __restrict__ out_dil,
    uint2* __restrict__ slots)
{
    const int blk = blockIdx.x;
    const int hv  = blk & 1;          // hh pair: {0,1} or {2,3}
    const int bc  = blk >> 1;
    const int b   = bc / MH;
    const int ch  = bc - b * MH;
    const int t   = threadIdx.x;

    __shared__ float carr[GG][MW];
    __shared__ float Rext[MW + 2];    // row-OR with the outward neighbor (hh==0 or hh==3)
    __shared__ float Rmid[MW + 2];    // this row only (interior hh)
    __shared__ unsigned int sm[4], sd[4];

    unsigned int local_m = 0;
    if (t < GG * MW) {
        int g = t / MW, cw = t - g * MW;
        unsigned char mv = coarse[(((size_t)b * GG + g) * MH + ch) * MW + cw];
        carr[g][cw] = (float)mv;
        if (hv == 0) local_m = mv;    // count mask once (hv0 blocks only)
    }
    if (t < MW) {
        float a  = (float)anyb[((size_t)b * MH + ch) * MW + t];
        float nb = 0.f;
        if (hv == 0) { if (ch > 0)      nb = (float)anyb[((size_t)b * MH + ch - 1) * MW + t]; }
        else         { if (ch < MH - 1) nb = (float)anyb[((size_t)b * MH + ch + 1) * MW + t]; }
        Rext[t + 1] = fmaxf(a, nb);
        Rmid[t + 1] = a;
    }
    if (t < 2) { Rext[t * (MW + 1)] = 0.f; Rmid[t * (MW + 1)] = 0.f; }
    __syncthreads();

    // 896 fine outputs: g(4) x hh2(2) x w(112)
    unsigned int local_d = 0;
    #pragma unroll
    for (int k = 0; k < 4; ++k) {
        int idx = t + 256 * k;
        if (idx < GG * 2 * 112) {
            int g   = idx / 224;
            int rem = idx - g * 224;
            int hh2 = rem / 112;
            int wfi = rem - hh2 * 112;
            int cw  = wfi >> 2;
            int wm  = wfi & 3;
            // hv0: hh=0 -> ext, hh=1 -> mid ; hv1: hh=2 -> mid, hh=3 -> ext
            const float* R = (hh2 == hv) ? Rext : Rmid;
            float d;
            if (wm == 0)      d = fmaxf(R[cw],     R[cw + 1]);
            else if (wm == 3) d = fmaxf(R[cw + 1], R[cw + 2]);
            else              d = R[cw + 1];
            float mv = carr[g][cw];
            int hh = hv * 2 + hh2;
            size_t o = (((size_t)b * GG + g) * 112 + (4 * ch + hh)) * 112 + wfi;
            out_mask[o] = mv;
            out_dil[o]  = d;
            local_d += (d > 0.5f) ? 1u : 0u;
        }
    }

    // dual wave reduction, no atomics
    #pragma unroll
    for (int off = 32; off; off >>= 1) {
        local_m += __shfl_down(local_m, off);
        local_d += __shfl_down(local_d, off);
    }
    if ((t & 63) == 0) { sm[t >> 6] = local_m; sd[t >> 6] = local_d; }
    __syncthreads();
    if (t == 0) {
        uint2 v;
        v.x = sm[0] + sm[1] + sm[2] + sm[3];
        v.y = sd[0] + sd[1] + sd[2] + sd[3];
        slots[blk] = v;               // overwrite: no init required
    }
}

// ---------- K3: reduce 1792 slots -> scalars ----------
__global__ __launch_bounds__(256) void masker_k3(
    const uint2* __restrict__ slots, float* __restrict__ out_scalars)
{
    int t = threadIdx.x;
    unsigned int m = 0, d = 0;
    for (int i = t; i < NB * MH * 2; i += 256) {
        uint2 v = slots[i]; m += v.x; d += v.y;
    }
    #pragma unroll
    for (int off = 32; off; off >>= 1) {
        m += __shfl_down(m, off);
        d += __shfl_down(d, off);
    }
    __shared__ unsigned int sm[4], sd[4];
    if ((t & 63) == 0) { sm[t >> 6] = m; sd[t >> 6] = d; }
    __syncthreads();
    if (t == 0) {
        out_scalars[0] = (float)(sm[0] + sm[1] + sm[2] + sm[3]) / 100352.0f;   // B*G*28*28
        out_scalars[1] = (float)(sd[0] + sd[1] + sd[2] + sd[3]) / 1605632.0f;  // B*G*112*112
        out_scalars[2] = 501760.0f;                                            // flops const
    }
}

extern "C" void kernel_launch(void* const* d_in, const int* in_sizes, int n_in,
                              void* d_out, int out_size, void* d_ws, size_t ws_size,
                              hipStream_t stream) {
    const float* x    = (const float*)d_in[0];
    const float* w    = (const float*)d_in[1];
    const float* bias = (const float*)d_in[2];
    const float* gum  = (const float*)d_in[3];

    float* out = (float*)d_out;
    const size_t n_mask = (size_t)NB * GG * 112 * 112;   // 1,605,632

    uint2*         slots  = (uint2*)d_ws;
    unsigned char* coarse = (unsigned char*)d_ws + 16384;
    unsigned char* anyb   = (unsigned char*)d_ws + 16384 + 100352;

    dim3 grid(NB * MH * 2);
    masker_k1<<<grid, 256, 0, stream>>>(x, w, bias, gum, coarse, anyb);
    masker_k2<<<grid, 256, 0, stream>>>(coarse, anyb, out, out + n_mask, slots);
    masker_k3<<<1, 256, 0, stream>>>(slots, out + 2 * n_mask);
}

// Round 6
// 34.986 us; speedup vs baseline: 6.9406x; 1.0528x over previous
//
#include <hip/hip_runtime.h>

#define MH 28
#define MW 28
#define CC 64
#define GG 4
#define NB 32

// ws layout (fast path):
//   [0, 7168)      : uint2 slots[896] (overwritten, no init)
//   [8192, +6.42MB): partial logits float [B][28][8 sp][8 o][28 cw]
// fallback path:
//   [0, 7168)      : slots
//   [8192, +100352): coarse uchar ; then anyb uchar (25088)

#define PLOG_OFF 8192
#define PLOG_BYTES ((size_t)NB * MH * 8 * 8 * MW * 4)   // 6,422,528

// ---------- K1: stream 8 channels x 56 rows, pool + partial projection ----------
// grid: B*8*2 = 512 blocks, 256 threads
__global__ __launch_bounds__(256) void masker_k1(
    const float* __restrict__ x, const float* __restrict__ w,
    float* __restrict__ plog)
{
    const int blk = blockIdx.x;
    const int b   = blk >> 4;
    const int sp  = (blk >> 1) & 7;     // channel octet
    const int hh2 = blk & 1;            // h-half: coarse rows [hh2*14, hh2*14+14)
    const int t   = threadIdx.x;

    __shared__ float pooled[8][14][MW];   // [c][chl][cw]  12.5 KB
    __shared__ float wl[8][8];            // [o][c-local]

    if (t < 64) wl[t >> 3][t & 7] = w[(t >> 3) * CC + sp * 8 + (t & 7)];

    // x slab: channels [sp*8, sp*8+8), rows [hh2*56, hh2*56+56)
    const float* xb = x + ((size_t)b * CC + sp * 8) * 12544 + (size_t)hh2 * 56 * 112;

    // 3136 cells = c(8) x chl(14) x cw(28); sequential q-walk => long runs
    #pragma unroll
    for (int k = 0; k < 13; ++k) {
        int p = t + 256 * k;
        if (p < 3136) {
            int c   = p / 392;
            int rem = p - c * 392;
            int chl = rem / MW;
            int cw  = rem - chl * MW;
            const float* base = xb + (size_t)c * 12544 + chl * 448 + cw * 4;
            float s = 0.f;
            #pragma unroll
            for (int hh = 0; hh < 4; ++hh) {
                float4 v = *(const float4*)(base + hh * 112);
                s += v.x + v.y + v.z + v.w;
            }
            pooled[c][chl][cw] = s * 0.0625f;
        }
    }
    __syncthreads();

    // partial projection: 3136 outputs = o(8) x chl(14) x cw(28), 8-chan dot
    #pragma unroll
    for (int k = 0; k < 13; ++k) {
        int p = t + 256 * k;
        if (p < 3136) {
            int o   = p / 392;
            int rem = p - o * 392;
            int chl = rem / MW;
            int cw  = rem - chl * MW;
            float acc = 0.f;
            #pragma unroll
            for (int c = 0; c < 8; ++c)
                acc += pooled[c][chl][cw] * wl[o][c];
            int ch = hh2 * 14 + chl;
            plog[(((size_t)b * MH + ch) * 8 + sp) * 224 + o * MW + cw] = acc;
        }
    }
}

// ---------- K2: combine + decide(3 rows) + dilate + outputs + slot counts ----------
// grid: B*MH = 896 blocks, 256 threads
__global__ __launch_bounds__(256) void masker_k2(
    const float* __restrict__ plog, const float* __restrict__ bias,
    const float* __restrict__ gum,
    float* __restrict__ out_mask, float* __restrict__ out_dil,
    uint2* __restrict__ slots)
{
    const int blk = blockIdx.x;
    const int b   = blk / MH;
    const int ch  = blk - b * MH;
    const int t   = threadIdx.x;

    __shared__ float L[3][8][MW];      // logits rows ch-1..ch+1
    __shared__ float dec[3][GG][MW];   // decisions, 0 for invalid rows
    __shared__ float R[3][MW + 2];
    __shared__ unsigned int sm[4], sd[4];

    // combine 8 partials + bias, 3 rows x (o,cw)=224
    if (t < 224) {
        int o = t / MW;
        #pragma unroll
        for (int r = 0; r < 3; ++r) {
            int row = ch - 1 + r;
            float acc = bias[o];
            if (row >= 0 && row < MH) {
                const float* p = plog + ((size_t)(b * MH + row) * 8) * 224 + t;
                acc += p[0] + p[224] + p[448] + p[672]
                     + p[896] + p[1120] + p[1344] + p[1568];   // fixed order
            }
            L[r][o][t - o * MW] = acc;
        }
    }
    __syncthreads();

    // gumbel decisions for 3 rows (T>0 scale argmax-invariant; ties -> idx 0)
    for (int idx = t; idx < 3 * GG * MW; idx += 256) {
        int r = idx / (GG * MW), rem = idx - r * (GG * MW);
        int g = rem / MW, cw = rem - g * MW;
        int row = ch - 1 + r;
        float d = 0.f;
        if (row >= 0 && row < MH) {
            float g0 = gum[((((size_t)b * 2 + 0) * GG + g) * MH + row) * MW + cw];
            float g1 = gum[((((size_t)b * 2 + 1) * GG + g) * MH + row) * MW + cw];
            d = (L[r][g][cw] + g0 >= L[r][g + 4][cw] + g1) ? 1.f : 0.f;
        }
        dec[r][g][cw] = d;
    }
    __syncthreads();

    unsigned int local_m = 0;
    if (t < GG * MW)
        local_m = (unsigned int)dec[1][t / MW][t - (t / MW) * MW];

    if (t < MW) {
        float a0 = fmaxf(fmaxf(dec[0][0][t], dec[0][1][t]), fmaxf(dec[0][2][t], dec[0][3][t]));
        float a1 = fmaxf(fmaxf(dec[1][0][t], dec[1][1][t]), fmaxf(dec[1][2][t], dec[1][3][t]));
        float a2 = fmaxf(fmaxf(dec[2][0][t], dec[2][1][t]), fmaxf(dec[2][2][t], dec[2][3][t]));
        R[0][t + 1] = fmaxf(a1, a0);
        R[1][t + 1] = a1;
        R[2][t + 1] = fmaxf(a1, a2);
    }
    if (t < 3) { R[t][0] = 0.f; R[t][MW + 1] = 0.f; }
    __syncthreads();

    // 1792 fine outputs: g(4) x hh(4) x w(112)
    unsigned int local_d = 0;
    #pragma unroll
    for (int k = 0; k < 7; ++k) {
        int idx = t + 256 * k;
        int g   = idx / 448;
        int rem = idx - g * 448;
        int hh  = rem / 112;
        int wfi = rem - hh * 112;
        int cw  = wfi >> 2;
        int wm  = wfi & 3;
        int rv  = (hh == 0) ? 0 : (hh == 3 ? 2 : 1);
        float d;
        if (wm == 0)      d = fmaxf(R[rv][cw],     R[rv][cw + 1]);
        else if (wm == 3) d = fmaxf(R[rv][cw + 1], R[rv][cw + 2]);
        else              d = R[rv][cw + 1];
        float mv = dec[1][g][cw];
        size_t o = (((size_t)b * GG + g) * 112 + (4 * ch + hh)) * 112 + wfi;
        out_mask[o] = mv;
        out_dil[o]  = d;
        local_d += (d > 0.5f) ? 1u : 0u;
    }

    #pragma unroll
    for (int off = 32; off; off >>= 1) {
        local_m += __shfl_down(local_m, off);
        local_d += __shfl_down(local_d, off);
    }
    if ((t & 63) == 0) { sm[t >> 6] = local_m; sd[t >> 6] = local_d; }
    __syncthreads();
    if (t == 0) {
        uint2 v;
        v.x = sm[0] + sm[1] + sm[2] + sm[3];
        v.y = sd[0] + sd[1] + sd[2] + sd[3];
        slots[blk] = v;
    }
}

// ---------- K3: reduce slots -> scalars ----------
__global__ __launch_bounds__(256) void masker_k3(
    const uint2* __restrict__ slots, float* __restrict__ out_scalars)
{
    int t = threadIdx.x;
    unsigned int m = 0, d = 0;
    for (int i = t; i < NB * MH; i += 256) { uint2 v = slots[i]; m += v.x; d += v.y; }
    #pragma unroll
    for (int off = 32; off; off >>= 1) { m += __shfl_down(m, off); d += __shfl_down(d, off); }
    __shared__ unsigned int sm[4], sd[4];
    if ((t & 63) == 0) { sm[t >> 6] = m; sd[t >> 6] = d; }
    __syncthreads();
    if (t == 0) {
        out_scalars[0] = (float)(sm[0] + sm[1] + sm[2] + sm[3]) / 100352.0f;
        out_scalars[1] = (float)(sd[0] + sd[1] + sd[2] + sd[3]) / 1605632.0f;
        out_scalars[2] = 501760.0f;
    }
}

// ================= fallback: proven round-2 path =================
__global__ __launch_bounds__(256) void masker_stage1(
    const float* __restrict__ x, const float* __restrict__ w,
    const float* __restrict__ bias, const float* __restrict__ gum,
    unsigned char* __restrict__ coarse, unsigned char* __restrict__ anyb)
{
    int b = blockIdx.x / MH, ch = blockIdx.x % MH, t = threadIdx.x;
    __shared__ float pooled[CC][MW];
    __shared__ float wlds[8 * CC];
    __shared__ float logits[8][MW];
    __shared__ unsigned char mlds[GG][MW];

    float g0 = 0.f, g1 = 0.f, bo = 0.f;
    if (t < GG * MW) {
        int g = t / MW, cw = t - g * MW;
        g0 = gum[((((size_t)b * 2 + 0) * GG + g) * MH + ch) * MW + cw];
        g1 = gum[((((size_t)b * 2 + 1) * GG + g) * MH + ch) * MW + cw];
    }
    if (t < 8 * MW) bo = bias[t / MW];
    if (t < 128) ((float4*)wlds)[t] = ((const float4*)w)[t];

    const float* xb = x + (size_t)b * CC * 112 * 112 + (size_t)(4 * ch) * 112;
    #pragma unroll
    for (int k = 0; k < 7; ++k) {
        int p = t + 256 * k, c = p / MW, cw = p - c * MW;
        const float* base = xb + (size_t)c * (112 * 112) + 4 * cw;
        float s = 0.f;
        #pragma unroll
        for (int hh = 0; hh < 4; ++hh) {
            float4 v = *(const float4*)(base + hh * 112);
            s += v.x + v.y + v.z + v.w;
        }
        pooled[c][cw] = s * 0.0625f;
    }
    __syncthreads();
    if (t < 8 * MW) {
        int o = t / MW, cw = t - o * MW;
        float acc = bo;
        #pragma unroll
        for (int c = 0; c < CC; ++c) acc += pooled[c][cw] * wlds[o * CC + c];
        logits[o][cw] = acc;
    }
    __syncthreads();
    if (t < GG * MW) {
        int g = t / MW, cw = t - g * MW;
        unsigned char mv = (logits[g][cw] + g0 >= logits[g + 4][cw] + g1) ? 1u : 0u;
        mlds[g][cw] = mv;
        coarse[(((size_t)b * GG + g) * MH + ch) * MW + cw] = mv;
    }
    __syncthreads();
    if (t < MW)
        anyb[((size_t)b * MH + ch) * MW + t] =
            mlds[0][t] | mlds[1][t] | mlds[2][t] | mlds[3][t];
}

__global__ __launch_bounds__(256) void masker_stage2(
    const unsigned char* __restrict__ coarse,
    const unsigned char* __restrict__ anyb,
    float* __restrict__ out_mask, float* __restrict__ out_dil,
    uint2* __restrict__ slots)
{
    int b = blockIdx.x / MH, ch = blockIdx.x % MH, t = threadIdx.x;
    __shared__ float carr[GG][MW];
    __shared__ float R[3][MW + 2];
    __shared__ unsigned int sm[4], sd[4];

    unsigned int local_m = 0;
    if (t < GG * MW) {
        int g = t / MW, cw = t - g * MW;
        unsigned char mv = coarse[(((size_t)b * GG + g) * MH + ch) * MW + cw];
        carr[g][cw] = (float)mv;
        local_m = mv;
    }
    if (t < MW) {
        float a  = (float)anyb[((size_t)b * MH + ch) * MW + t];
        float am = (ch > 0)      ? (float)anyb[((size_t)b * MH + ch - 1) * MW + t] : 0.f;
        float ap = (ch < MH - 1) ? (float)anyb[((size_t)b * MH + ch + 1) * MW + t] : 0.f;
        R[0][t + 1] = fmaxf(a, am);
        R[1][t + 1] = a;
        R[2][t + 1] = fmaxf(a, ap);
    }
    if (t < 3) { R[t][0] = 0.f; R[t][MW + 1] = 0.f; }
    __syncthreads();

    unsigned int local_d = 0;
    #pragma unroll
    for (int k = 0; k < 7; ++k) {
        int idx = t + 256 * k;
        int g = idx / 448, rem = idx - g * 448;
        int hh = rem / 112, wfi = rem - hh * 112;
        int cw = wfi >> 2, wm = wfi & 3;
        int rv = (hh == 0) ? 0 : (hh == 3 ? 2 : 1);
        float d;
        if (wm == 0)      d = fmaxf(R[rv][cw],     R[rv][cw + 1]);
        else if (wm == 3) d = fmaxf(R[rv][cw + 1], R[rv][cw + 2]);
        else              d = R[rv][cw + 1];
        float mv = carr[g][cw];
        size_t o = (((size_t)b * GG + g) * 112 + (4 * ch + hh)) * 112 + wfi;
        out_mask[o] = mv;
        out_dil[o]  = d;
        local_d += (d > 0.5f) ? 1u : 0u;
    }
    #pragma unroll
    for (int off = 32; off; off >>= 1) {
        local_m += __shfl_down(local_m, off);
        local_d += __shfl_down(local_d, off);
    }
    if ((t & 63) == 0) { sm[t >> 6] = local_m; sd[t >> 6] = local_d; }
    __syncthreads();
    if (t == 0) {
        uint2 v;
        v.x = sm[0] + sm[1] + sm[2] + sm[3];
        v.y = sd[0] + sd[1] + sd[2] + sd[3];
        slots[blockIdx.x] = v;
    }
}

extern "C" void kernel_launch(void* const* d_in, const int* in_sizes, int n_in,
                              void* d_out, int out_size, void* d_ws, size_t ws_size,
                              hipStream_t stream) {
    const float* x    = (const float*)d_in[0];
    const float* w    = (const float*)d_in[1];
    const float* bias = (const float*)d_in[2];
    const float* gum  = (const float*)d_in[3];

    float* out = (float*)d_out;
    const size_t n_mask = (size_t)NB * GG * 112 * 112;   // 1,605,632

    uint2* slots = (uint2*)d_ws;

    if (ws_size >= PLOG_OFF + PLOG_BYTES) {
        float* plog = (float*)((char*)d_ws + PLOG_OFF);
        masker_k1<<<dim3(NB * 8 * 2), 256, 0, stream>>>(x, w, plog);
        masker_k2<<<dim3(NB * MH), 256, 0, stream>>>(plog, bias, gum,
                                                     out, out + n_mask, slots);
    } else {
        unsigned char* coarse = (unsigned char*)d_ws + 8192;
        unsigned char* anyb   = (unsigned char*)d_ws + 8192 + 100352;
        masker_stage1<<<dim3(NB * MH), 256, 0, stream>>>(x, w, bias, gum, coarse, anyb);
        masker_stage2<<<dim3(NB * MH), 256, 0, stream>>>(coarse, anyb,
                                                         out, out + n_mask, slots);
    }
    masker_k3<<<1, 256, 0, stream>>>(slots, out + 2 * n_mask);
}